// Round 6
// baseline (5246.487 us; speedup 1.0000x reference)
//
#include <hip/hip_runtime.h>

#define B_ 128
#define T_ 512
#define E_ 256
#define H_ 512
#define NSLICE 16   // h-slices per (dir, bgroup)
#define NBG 4       // batch groups of 32 rows
#define AGENT __HIP_MEMORY_SCOPE_AGENT

typedef float f32x16 __attribute__((ext_vector_type(16)));
typedef unsigned short u16x8 __attribute__((ext_vector_type(8)));
typedef __bf16 bf16x8 __attribute__((ext_vector_type(8)));
typedef int i32x4 __attribute__((ext_vector_type(4)));
typedef unsigned long long u64;

union U8 { u16x8 u; bf16x8 b; i32x4 d; u64 q[2]; };

__device__ __forceinline__ unsigned short f2bf(float f) {
    unsigned u = __float_as_uint(f);
    return (unsigned short)((u + 0x7FFFu + ((u >> 16) & 1u)) >> 16);
}
__device__ __forceinline__ float bf2f(unsigned short s) {
    return __uint_as_float(((unsigned)s) << 16);
}
__device__ __forceinline__ float sigm(float x) { return 1.f / (1.f + __expf(-x)); }
__device__ __forceinline__ float tanh_f(float x) {
    float e = __expf(2.f * x);
    return 1.f - 2.f / (e + 1.f);   // inf-safe at both ends
}

// hbuf frag-major layout (shorts): [dir][buf][bg][c:32][lane:64][j:8]
// element (dir,buf,bg, batch row b=bg*32+rr, col k) lives at
//   c=k>>4, lane=((k>>3)&1)*32+rr, j=k&7
__device__ __forceinline__ int hfm_base(int dir, int buf, int bg) {
    return ((dir * 2 + buf) * NBG + bg) * (32 * 64 * 8);
}

// ---------------- gather: x_bf16[b][t][e] = bf16(emb[inputs[b][t]][e]) --------
__global__ void gather_k(const int* __restrict__ idx, const float* __restrict__ emb,
                         unsigned short* __restrict__ x) {
    int row = blockIdx.x;          // b*T + t
    int e = threadIdx.x;           // 0..255
    int id = idx[row];
    x[row * E_ + e] = f2bf(emb[id * E_ + e]);
}

// ---------------- persistent bidirectional GRU ----------------
// grid: 128 WGs = dir(2) x bgroup(4) x slice(16); 192 threads = 3 waves (r,z,n)
// Per-step cross-WG exchange (all through sc0sc1 / LLC, NO cache-wide fences):
//   producer: n-wave -> LDS transpose (WG tile = exactly 2 frag-major lines)
//     -> waves 0,1 store 1KB each as coalesced 8B relaxed-atomic stores
//     -> vmcnt(0) -> barrier -> one relaxed flag store (value t+1).
//   consumer: wid0 polls 16 spread flag words (relaxed atomic gather + __any)
//     -> barrier -> all waves load h as coalesced 8B relaxed-atomic loads.
// No buffer_inv: L2 stays warm for x (R0-R4 refetched ~780MB of x through L3).
__global__ __launch_bounds__(192, 1) void gru_k(
    const unsigned short* __restrict__ x,
    const float* __restrict__ Wih_f, const float* __restrict__ Whh_f,
    const float* __restrict__ bih_f, const float* __restrict__ bhh_f,
    const float* __restrict__ Wih_b, const float* __restrict__ Whh_b,
    const float* __restrict__ bih_b, const float* __restrict__ bhh_b,
    unsigned short* __restrict__ hbuf,   // frag-major, 512 KB
    unsigned int* __restrict__ flags)    // [2][4][16] words, 64B stride
{
    const int wg  = blockIdx.x;
    const int dir = wg >> 6;          // 0 fwd, 1 bwd
    const int bg  = (wg >> 4) & 3;
    const int sl  = wg & 15;
    const int wid = threadIdx.x >> 6;   // 0=r 1=z 2=n
    const int lane = threadIdx.x & 63;
    const int l31 = lane & 31;
    const int lh  = lane >> 5;          // 0/1

    const float* Wih = dir ? Wih_b : Wih_f;
    const float* Whh = dir ? Whh_b : Whh_f;
    const float* bih = dir ? bih_b : bih_f;
    const float* bhh = dir ? bhh_b : bhh_f;

    // W row this lane serves (B-operand col): gate block + slice + lane col
    const int gcol = wid * H_ + sl * 32 + l31;

    // ---- load persistent B-fragments: 48 x (16B/lane) = 192 VGPRs ----
    U8 Bf[48];
#pragma unroll
    for (int c = 0; c < 16; ++c) {               // x-part K=0..255
        const float* p = Wih + gcol * E_ + c * 16 + 8 * lh;
        float4 a = *(const float4*)p;
        float4 b = *(const float4*)(p + 4);
        U8 v;
        v.u[0] = f2bf(a.x); v.u[1] = f2bf(a.y); v.u[2] = f2bf(a.z); v.u[3] = f2bf(a.w);
        v.u[4] = f2bf(b.x); v.u[5] = f2bf(b.y); v.u[6] = f2bf(b.z); v.u[7] = f2bf(b.w);
        Bf[c] = v;
    }
#pragma unroll
    for (int c = 0; c < 32; ++c) {               // h-part K=256..767
        const float* p = Whh + gcol * H_ + c * 16 + 8 * lh;
        float4 a = *(const float4*)p;
        float4 b = *(const float4*)(p + 4);
        U8 v;
        v.u[0] = f2bf(a.x); v.u[1] = f2bf(a.y); v.u[2] = f2bf(a.z); v.u[3] = f2bf(a.w);
        v.u[4] = f2bf(b.x); v.u[5] = f2bf(b.y); v.u[6] = f2bf(b.z); v.u[7] = f2bf(b.w);
        Bf[16 + c] = v;
    }

    const float bi = bih[gcol];
    const float bh = bhh[gcol];

    const int b = bg * 32 + l31;                 // A-operand row (batch)
    const unsigned short* xrow = x + (b * T_) * E_;

    unsigned int* fgrp = flags + (dir * NBG + bg) * 16 * 16;   // 64B-stride words
    const unsigned int* fpoll = fgrp + (lane & 15) * 16;       // wid0 gather addr
    unsigned int* fmine = fgrp + sl * 16;                      // producer's word

    unsigned short* hfm[2] = { hbuf + hfm_base(dir, 0, bg), hbuf + hfm_base(dir, 1, bg) };

    __shared__ float lds_r[16][64];
    __shared__ float lds_z[16][64];
    __shared__ float lds_t[32][33];              // h-tile transpose buffer

    f32x16 hold;                                 // n-wave: own h slice, f32
#pragma unroll
    for (int i = 0; i < 16; ++i) hold[i] = 0.f;

    for (int t = 0; t < T_; ++t) {
        const int tx = dir ? (T_ - 1 - t) : t;

        // split accumulators: halve the exposed dependent-MFMA latency
        f32x16 acc, accB, acc2, acc2b;
#pragma unroll
        for (int i = 0; i < 16; ++i) { acc[i] = bi; accB[i] = 0.f; acc2[i] = bh; acc2b[i] = 0.f; }

        // x-part first: loads + MFMAs have no h dependency -> overlap the poll
        {
            const unsigned short* xp = xrow + tx * E_;
            U8 ax[16];
#pragma unroll
            for (int c = 0; c < 16; ++c) ax[c].u = *(const u16x8*)(xp + c * 16 + 8 * lh);
#pragma unroll
            for (int c = 0; c < 16; c += 2) {
                acc  = __builtin_amdgcn_mfma_f32_32x32x16_bf16(ax[c].b,     Bf[c].b,     acc,  0, 0, 0);
                accB = __builtin_amdgcn_mfma_f32_32x32x16_bf16(ax[c + 1].b, Bf[c + 1].b, accB, 0, 0, 0);
            }
        }

        if (t > 0) {
            if (wid == 0) {
                // poll: gather the 16 spread flag words (sc0sc1, LLC-direct)
                for (;;) {
                    unsigned v = __hip_atomic_load(fpoll, __ATOMIC_RELAXED, AGENT);
                    if (!__any((int)v < t)) break;
                    __builtin_amdgcn_s_sleep(1);
                }
            }
            __syncthreads();                     // release wid1/wid2

            // h A-frags: coalesced 8B relaxed-atomic loads (sc0sc1, hazard-tracked)
            const unsigned short* hsrc = hfm[t & 1];
#pragma unroll
            for (int c = 0; c < 32; c += 2) {
                const u64* p0 = (const u64*)(hsrc + c * 512 + lane * 8);
                const u64* p1 = (const u64*)(hsrc + (c + 1) * 512 + lane * 8);
                U8 a0, a1;
                a0.q[0] = __hip_atomic_load(p0,     __ATOMIC_RELAXED, AGENT);
                a0.q[1] = __hip_atomic_load(p0 + 1, __ATOMIC_RELAXED, AGENT);
                a1.q[0] = __hip_atomic_load(p1,     __ATOMIC_RELAXED, AGENT);
                a1.q[1] = __hip_atomic_load(p1 + 1, __ATOMIC_RELAXED, AGENT);
                acc2  = __builtin_amdgcn_mfma_f32_32x32x16_bf16(a0.b, Bf[16 + c].b,     acc2,  0, 0, 0);
                acc2b = __builtin_amdgcn_mfma_f32_32x32x16_bf16(a1.b, Bf[16 + c + 1].b, acc2b, 0, 0, 0);
            }
        }

        // fold split accumulators
#pragma unroll
        for (int i = 0; i < 16; ++i) { acc[i] += accB[i]; acc2[i] += acc2b[i]; }

        // gates: r,z waves publish to LDS; n wave does the update
        if (wid == 0) {
#pragma unroll
            for (int i = 0; i < 16; ++i) lds_r[i][lane] = sigm(acc[i] + acc2[i]);
        } else if (wid == 1) {
#pragma unroll
            for (int i = 0; i < 16; ++i) lds_z[i][lane] = sigm(acc[i] + acc2[i]);
        }
        __syncthreads();

        if (wid == 2) {
            // compute new h, write the 32x32 tile to LDS (transpose staging)
#pragma unroll
            for (int i = 0; i < 16; ++i) {
                float r = lds_r[i][lane];
                float z = lds_z[i][lane];
                float n = tanh_f(acc[i] + r * acc2[i]);   // xn + r*(hn+b_hh_n)
                float hn = (1.f - z) * n + z * hold[i];
                hold[i] = hn;
                int rr = (i & 3) + 8 * (i >> 2) + 4 * lh;  // C/D row map
                lds_t[rr][l31] = hn;
            }
        }
        __syncthreads();

        if (wid < 2) {
            // WG tile = exactly 2 frag-major lines; wave wid stores line sl*2+wid.
            // lane stores shorts [lane*8 .. lane*8+7]: value(row=lane&31,
            // col_local = wid*16 + (lane>>5)*8 + j) -> two coalesced 8B stores.
            float f0 = lds_t[l31][wid * 16 + lh * 8 + 0];
            float f1 = lds_t[l31][wid * 16 + lh * 8 + 1];
            float f2 = lds_t[l31][wid * 16 + lh * 8 + 2];
            float f3 = lds_t[l31][wid * 16 + lh * 8 + 3];
            float f4 = lds_t[l31][wid * 16 + lh * 8 + 4];
            float f5 = lds_t[l31][wid * 16 + lh * 8 + 5];
            float f6 = lds_t[l31][wid * 16 + lh * 8 + 6];
            float f7 = lds_t[l31][wid * 16 + lh * 8 + 7];
            unsigned d0 = (unsigned)f2bf(f0) | ((unsigned)f2bf(f1) << 16);
            unsigned d1 = (unsigned)f2bf(f2) | ((unsigned)f2bf(f3) << 16);
            unsigned d2 = (unsigned)f2bf(f4) | ((unsigned)f2bf(f5) << 16);
            unsigned d3 = (unsigned)f2bf(f6) | ((unsigned)f2bf(f7) << 16);
            u64 q0 = (u64)d0 | ((u64)d1 << 32);
            u64 q1 = (u64)d2 | ((u64)d3 << 32);
            unsigned short* sb = hfm[(t + 1) & 1] + (sl * 2 + wid) * 512 + lane * 8;
            __hip_atomic_store((u64*)sb,       q0, __ATOMIC_RELAXED, AGENT);
            __hip_atomic_store((u64*)(sb + 4), q1, __ATOMIC_RELAXED, AGENT);
            // both 8B stores acked at the LLC before anyone bumps the flag
            asm volatile("s_waitcnt vmcnt(0)" ::: "memory");
        }
        __syncthreads();

        if (wid == 2 && lane == 0)
            __hip_atomic_store(fmine, (unsigned)(t + 1), __ATOMIC_RELAXED, AGENT);
    }
}

// ---------------- FC head: out[b] = sigmoid(concat(h_f,h_b) . fc_w + fc_b) ----
__global__ void fc_k(const unsigned short* __restrict__ hbuf,
                     const float* __restrict__ fcw, const float* __restrict__ fcb,
                     float* __restrict__ out) {
    int bb = blockIdx.x;
    int l = threadIdx.x;       // 64 threads = 1 wave
    int bg = bb >> 5, rr = bb & 31;
    float s = 0.f;
    for (int col = l; col < H_; col += 64) {
        int c = col >> 4, hi = (col >> 3) & 1, j = col & 7;
        int off = c * 512 + (hi * 32 + rr) * 8 + j;
        s += bf2f(hbuf[hfm_base(0, 0, bg) + off]) * fcw[col];        // fwd, buf 0
        s += bf2f(hbuf[hfm_base(1, 0, bg) + off]) * fcw[H_ + col];   // bwd, buf 0
    }
#pragma unroll
    for (int o = 32; o > 0; o >>= 1) s += __shfl_down(s, o);
    if (l == 0) out[bb] = sigm(s + fcb[0]);
}

extern "C" void kernel_launch(void* const* d_in, const int* in_sizes, int n_in,
                              void* d_out, int out_size, void* d_ws, size_t ws_size,
                              hipStream_t stream) {
    (void)in_sizes; (void)n_in; (void)out_size; (void)ws_size;
    const int*   inputs = (const int*)d_in[0];
    const float* emb    = (const float*)d_in[1];
    const float* Wih_f  = (const float*)d_in[2];
    const float* Whh_f  = (const float*)d_in[3];
    const float* bih_f  = (const float*)d_in[4];
    const float* bhh_f  = (const float*)d_in[5];
    const float* Wih_b  = (const float*)d_in[6];
    const float* Whh_b  = (const float*)d_in[7];
    const float* bih_b  = (const float*)d_in[8];
    const float* bhh_b  = (const float*)d_in[9];
    const float* fcw    = (const float*)d_in[10];
    const float* fcb    = (const float*)d_in[11];
    float* out = (float*)d_out;

    char* w = (char*)d_ws;
    unsigned short* xbuf = (unsigned short*)w;                          // 33,554,432 B
    unsigned short* hbuf = (unsigned short*)(w + 33554432);             //    524,288 B
    unsigned int*   flags= (unsigned int*)(w + 33554432 + 524288);      //      8,192 B

    hipMemsetAsync(flags, 0, 2 * NBG * 16 * 64, stream);
    gather_k<<<B_ * T_, E_, 0, stream>>>(inputs, emb, xbuf);
    gru_k<<<128, 192, 0, stream>>>(xbuf, Wih_f, Whh_f, bih_f, bhh_f,
                                   Wih_b, Whh_b, bih_b, bhh_b, hbuf, flags);
    fc_k<<<B_, 64, 0, stream>>>(hbuf, fcw, fcb, out);
}

// Round 7
// 3552.879 us; speedup vs baseline: 1.4767x; 1.4767x over previous
//
#include <hip/hip_runtime.h>

#define B_ 128
#define T_ 512
#define E_ 256
#define H_ 512
#define NBG 4       // batch groups of 32 rows
#define AGENT __HIP_MEMORY_SCOPE_AGENT

typedef float f32x16 __attribute__((ext_vector_type(16)));
typedef unsigned short u16x8 __attribute__((ext_vector_type(8)));
typedef __bf16 bf16x8 __attribute__((ext_vector_type(8)));
typedef int i32x4 __attribute__((ext_vector_type(4)));
typedef unsigned u32;

union U8 { u16x8 u; bf16x8 b; i32x4 d; };

__device__ __forceinline__ unsigned short f2bf(float f) {
    unsigned u = __float_as_uint(f);
    return (unsigned short)((u + 0x7FFFu + ((u >> 16) & 1u)) >> 16);
}
__device__ __forceinline__ float bf2f(unsigned short s) {
    return __uint_as_float(((unsigned)s) << 16);
}
__device__ __forceinline__ float sigm(float x) { return 1.f / (1.f + __expf(-x)); }
__device__ __forceinline__ float tanh_f(float x) {
    float e = __expf(2.f * x);
    return 1.f - 2.f / (e + 1.f);   // inf-safe at both ends
}

// Tagged h buffer (u32 words): word = {bf16 value (low16) | step tag (high16)}.
// Layout per (dir,buf,bg): [line c:32][lane:64][pair j:8] u32  (tile = 16384 u32).
// Value for (row, col k): c = k>>4, lane = ((k>>3)&1)*32 + row, j = k&7.
// Tag for h_t is t (1..512); ws poison 0xAAAA never matches -> no init needed.
__device__ __forceinline__ int hw_base(int dir, int buf, int bg) {
    return ((dir * 2 + buf) * NBG + bg) * 16384;
}

// ---------------- gather: x_bf16[b][t][e] = bf16(emb[inputs[b][t]][e]) --------
__global__ void gather_k(const int* __restrict__ idx, const float* __restrict__ emb,
                         unsigned short* __restrict__ x) {
    int row = blockIdx.x;          // b*T + t
    int e = threadIdx.x;           // 0..255
    int id = idx[row];
    x[row * E_ + e] = f2bf(emb[id * E_ + e]);
}

// ---------------- persistent bidirectional GRU ----------------
// grid: 128 WGs = dir(2) x bgroup(4) x slice(16); 192 threads = 3 waves (r,z,n)
// Exchange protocol: tag-in-word. NO flags, NO producer drain, NO fences:
//   producer: 16 relaxed u32 {val|tag} stores, fire-and-forget.
//   consumer: each wave asm-loads its 1/3 of the tagged tile (dwordx4 sc0sc1),
//     retries until all tags == t, packs low halves to bf16 frags, stages to
//     LDS; one barrier; all waves MFMA from LDS.
// Visibility rides with the data word (4B single-copy atomic at the LLC).
__global__ __launch_bounds__(192, 1) void gru_k(
    const unsigned short* __restrict__ x,
    const float* __restrict__ Wih_f, const float* __restrict__ Whh_f,
    const float* __restrict__ bih_f, const float* __restrict__ bhh_f,
    const float* __restrict__ Wih_b, const float* __restrict__ Whh_b,
    const float* __restrict__ bih_b, const float* __restrict__ bhh_b,
    u32* __restrict__ hbuf)              // tagged, 1 MB
{
    const int wg  = blockIdx.x;
    const int dir = wg >> 6;          // 0 fwd, 1 bwd
    const int bg  = (wg >> 4) & 3;
    const int sl  = wg & 15;
    const int wid = threadIdx.x >> 6;   // 0=r 1=z 2=n
    const int lane = threadIdx.x & 63;
    const int l31 = lane & 31;
    const int lh  = lane >> 5;          // 0/1

    const float* Wih = dir ? Wih_b : Wih_f;
    const float* Whh = dir ? Whh_b : Whh_f;
    const float* bih = dir ? bih_b : bih_f;
    const float* bhh = dir ? bhh_b : bhh_f;

    // W row this lane serves (B-operand col): gate block + slice + lane col
    const int gcol = wid * H_ + sl * 32 + l31;

    // ---- load persistent B-fragments: 48 x (16B/lane) = 192 VGPRs ----
    U8 Bf[48];
#pragma unroll
    for (int c = 0; c < 16; ++c) {               // x-part K=0..255
        const float* p = Wih + gcol * E_ + c * 16 + 8 * lh;
        float4 a = *(const float4*)p;
        float4 b = *(const float4*)(p + 4);
        U8 v;
        v.u[0] = f2bf(a.x); v.u[1] = f2bf(a.y); v.u[2] = f2bf(a.z); v.u[3] = f2bf(a.w);
        v.u[4] = f2bf(b.x); v.u[5] = f2bf(b.y); v.u[6] = f2bf(b.z); v.u[7] = f2bf(b.w);
        Bf[c] = v;
    }
#pragma unroll
    for (int c = 0; c < 32; ++c) {               // h-part K=256..767
        const float* p = Whh + gcol * H_ + c * 16 + 8 * lh;
        float4 a = *(const float4*)p;
        float4 b = *(const float4*)(p + 4);
        U8 v;
        v.u[0] = f2bf(a.x); v.u[1] = f2bf(a.y); v.u[2] = f2bf(a.z); v.u[3] = f2bf(a.w);
        v.u[4] = f2bf(b.x); v.u[5] = f2bf(b.y); v.u[6] = f2bf(b.z); v.u[7] = f2bf(b.w);
        Bf[16 + c] = v;
    }

    const float bi = bih[gcol];
    const float bh = bhh[gcol];

    const int b = bg * 32 + l31;                 // A-operand row (batch)
    const unsigned short* xrow = x + (b * T_) * E_;

    __shared__ i32x4 lds_h[32][64];              // staged packed h frags, 32 KB
    __shared__ float lds_r[16][64];
    __shared__ float lds_z[16][64];

    // this wave's frag subset for staging: 11/11/10
    const int cf0 = wid * 11;
    const int ncf = (wid == 2) ? 10 : 11;

    f32x16 hold;                                 // n-wave: own h slice, f32
#pragma unroll
    for (int i = 0; i < 16; ++i) hold[i] = 0.f;

    for (int t = 0; t < T_; ++t) {
        const int tx = dir ? (T_ - 1 - t) : t;

        f32x16 acc, accB, acc2, acc2b;           // split accumulators
#pragma unroll
        for (int i = 0; i < 16; ++i) { acc[i] = bi; accB[i] = 0.f; acc2[i] = bh; acc2b[i] = 0.f; }

        // x-part first (no h dependency; absorbs load latency while producers run)
        {
            const unsigned short* xp = xrow + tx * E_;
            U8 ax[16];
#pragma unroll
            for (int c = 0; c < 16; ++c) ax[c].u = *(const u16x8*)(xp + c * 16 + 8 * lh);
#pragma unroll
            for (int c = 0; c < 16; c += 2) {
                acc  = __builtin_amdgcn_mfma_f32_32x32x16_bf16(ax[c].b,     Bf[c].b,     acc,  0, 0, 0);
                accB = __builtin_amdgcn_mfma_f32_32x32x16_bf16(ax[c + 1].b, Bf[c + 1].b, accB, 0, 0, 0);
            }
        }

        if (t > 0) {
            const u32 texp = (u32)t << 16;
            const u32* hp = hbuf + hw_base(dir, t & 1, bg);
            i32x4 lo[11], hi[11];
            for (;;) {
#pragma unroll
                for (int k = 0; k < 11; ++k) {
                    if (k < ncf) {
                        const u32* p = hp + (cf0 + k) * 512 + lane * 8;
                        asm volatile("global_load_dwordx4 %0, %1, off sc0 sc1"
                                     : "=&v"(lo[k]) : "v"(p) : "memory");
                        asm volatile("global_load_dwordx4 %0, %1, off sc0 sc1"
                                     : "=&v"(hi[k]) : "v"(p + 4) : "memory");
                    }
                }
                asm volatile("s_waitcnt vmcnt(0)" ::: "memory");
                __builtin_amdgcn_sched_barrier(0);
                u32 bad = 0;
#pragma unroll
                for (int k = 0; k < 11; ++k) {
                    if (k < ncf) {
#pragma unroll
                        for (int j = 0; j < 4; ++j) {
                            bad |= ((u32)lo[k][j] ^ texp) & 0xFFFF0000u;
                            bad |= ((u32)hi[k][j] ^ texp) & 0xFFFF0000u;
                        }
                    }
                }
                if (!__any(bad != 0)) break;
            }
            // pack value halves -> bf16 frags, stage to LDS
#pragma unroll
            for (int k = 0; k < 11; ++k) {
                if (k < ncf) {
                    i32x4 pk;
                    pk[0] = (lo[k][0] & 0xFFFF) | (lo[k][1] << 16);
                    pk[1] = (lo[k][2] & 0xFFFF) | (lo[k][3] << 16);
                    pk[2] = (hi[k][0] & 0xFFFF) | (hi[k][1] << 16);
                    pk[3] = (hi[k][2] & 0xFFFF) | (hi[k][3] << 16);
                    lds_h[cf0 + k][lane] = pk;
                }
            }
        }
        __syncthreads();                         // B1: staged h visible

        if (t > 0) {
#pragma unroll
            for (int c = 0; c < 32; c += 2) {
                U8 a0, a1;
                a0.d = lds_h[c][lane];
                a1.d = lds_h[c + 1][lane];
                acc2  = __builtin_amdgcn_mfma_f32_32x32x16_bf16(a0.b, Bf[16 + c].b,     acc2,  0, 0, 0);
                acc2b = __builtin_amdgcn_mfma_f32_32x32x16_bf16(a1.b, Bf[16 + c + 1].b, acc2b, 0, 0, 0);
            }
        }

        // fold split accumulators
#pragma unroll
        for (int i = 0; i < 16; ++i) { acc[i] += accB[i]; acc2[i] += acc2b[i]; }

        // gates: r,z waves publish to LDS; n wave does the update
        if (wid == 0) {
#pragma unroll
            for (int i = 0; i < 16; ++i) lds_r[i][lane] = sigm(acc[i] + acc2[i]);
        } else if (wid == 1) {
#pragma unroll
            for (int i = 0; i < 16; ++i) lds_z[i][lane] = sigm(acc[i] + acc2[i]);
        }
        __syncthreads();                         // B2

        if (wid == 2) {
            const u32 tago = (u32)(t + 1) << 16;
            const int c0 = sl * 2 + (l31 >> 4);
            const int lp = ((l31 >> 3) & 1) * 32;
            u32* outp = hbuf + hw_base(dir, (t + 1) & 1, bg)
                      + c0 * 512 + lp * 8 + (l31 & 7);
#pragma unroll
            for (int i = 0; i < 16; ++i) {
                float r = lds_r[i][lane];
                float z = lds_z[i][lane];
                float n = tanh_f(acc[i] + r * acc2[i]);   // xn + r*(hn+b_hh_n)
                float hn = (1.f - z) * n + z * hold[i];
                hold[i] = hn;
                int rr = (i & 3) + 8 * (i >> 2) + 4 * lh;  // C/D row map
                // fire-and-forget: visibility rides with the tagged word
                __hip_atomic_store(outp + rr * 8, (u32)f2bf(hn) | tago,
                                   __ATOMIC_RELAXED, AGENT);
            }
        }
    }
}

// ---------------- FC head: out[b] = sigmoid(concat(h_f,h_b) . fc_w + fc_b) ----
__global__ void fc_k(const u32* __restrict__ hbuf,
                     const float* __restrict__ fcw, const float* __restrict__ fcb,
                     float* __restrict__ out) {
    int bb = blockIdx.x;
    int l = threadIdx.x;       // 64 threads = 1 wave
    int bg = bb >> 5, rr = bb & 31;
    float s = 0.f;
    for (int col = l; col < H_; col += 64) {
        int off = (col >> 4) * 512 + ((((col >> 3) & 1) << 5) | rr) * 8 + (col & 7);
        s += bf2f((unsigned short)(hbuf[hw_base(0, 0, bg) + off] & 0xFFFF)) * fcw[col];
        s += bf2f((unsigned short)(hbuf[hw_base(1, 0, bg) + off] & 0xFFFF)) * fcw[H_ + col];
    }
#pragma unroll
    for (int o = 32; o > 0; o >>= 1) s += __shfl_down(s, o);
    if (l == 0) out[bb] = sigm(s + fcb[0]);
}

extern "C" void kernel_launch(void* const* d_in, const int* in_sizes, int n_in,
                              void* d_out, int out_size, void* d_ws, size_t ws_size,
                              hipStream_t stream) {
    (void)in_sizes; (void)n_in; (void)out_size; (void)ws_size;
    const int*   inputs = (const int*)d_in[0];
    const float* emb    = (const float*)d_in[1];
    const float* Wih_f  = (const float*)d_in[2];
    const float* Whh_f  = (const float*)d_in[3];
    const float* bih_f  = (const float*)d_in[4];
    const float* bhh_f  = (const float*)d_in[5];
    const float* Wih_b  = (const float*)d_in[6];
    const float* Whh_b  = (const float*)d_in[7];
    const float* bih_b  = (const float*)d_in[8];
    const float* bhh_b  = (const float*)d_in[9];
    const float* fcw    = (const float*)d_in[10];
    const float* fcb    = (const float*)d_in[11];
    float* out = (float*)d_out;

    char* w = (char*)d_ws;
    unsigned short* xbuf = (unsigned short*)w;                // 33,554,432 B
    u32* hbuf = (u32*)(w + 33554432);                         //  1,048,576 B (tagged)
    // no init needed: 0xAA poison -> tag 0xAAAA never matches a real tag (1..512)

    gather_k<<<B_ * T_, E_, 0, stream>>>(inputs, emb, xbuf);
    gru_k<<<128, 192, 0, stream>>>(xbuf, Wih_f, Whh_f, bih_f, bhh_f,
                                   Wih_b, Whh_b, bih_b, bhh_b, hbuf);
    fc_k<<<B_, 64, 0, stream>>>(hbuf, fcw, fcb, out);
}